// Round 11
// baseline (405.452 us; speedup 1.0000x reference)
//
#include <hip/hip_runtime.h>
#include <math.h>

#define TOPK 8
#define NE   128
#define MARGIN 1.5e-5f

typedef _Float16 h8 __attribute__((ext_vector_type(8)));
typedef _Float16 h4 __attribute__((ext_vector_type(4)));
typedef float    f4 __attribute__((ext_vector_type(4)));

// Row-pair-packed swizzled byte address for a [rows][32 halfs] tile.
// Two 64-B rows share a 128-B line; XOR spreads 8 lines across 8 16-B slots.
__device__ __forceinline__ int adr(int row, int kb) {
  const int line = row >> 1;
  return line * 128 + ((((row & 1) << 6) | kb) ^ ((line & 7) << 4));
}

#define GLOAD_LDS16(g, l)                                              \
  __builtin_amdgcn_global_load_lds(                                    \
      (const __attribute__((address_space(1))) void*)(g),              \
      (__attribute__((address_space(3))) void*)(l), 16, 0, 0)

// ---------------- Kernel 0: split W into fp16 hi + scaled lo ----------------
__global__ __launch_bounds__(256) void router_wsplit(
    const float* __restrict__ W, _Float16* __restrict__ whi,
    _Float16* __restrict__ wlo, int n4) {
  const int i = blockIdx.x * 256 + threadIdx.x;
  if (i < n4) {
    const float4 v = ((const float4*)W)[i];
    h4 hi, lo;
#pragma unroll
    for (int q = 0; q < 4; ++q) {
      const float vq = ((const float*)&v)[q];
      const _Float16 h = (_Float16)vq;
      hi[q] = h;
      lo[q] = (_Float16)((vq - (float)h) * 2048.0f);  // lo' = lo * 2^11
    }
    ((h4*)whi)[i] = hi;
    ((h4*)wlo)[i] = lo;
  }
}

// ---------------- Pass 1: split-fp16 MFMA GEMM; A in registers, B via DMA dbuf ----------------
// 256 threads = 4 waves; tile 64 tok x 128 exp; BK=32; ONE barrier per K-tile.
// A fragments loaded straight from global x into regs (no LDS); B double-buffered
// via global_load_lds, drained by the next tile's __syncthreads (full tile of cover).
__global__ __launch_bounds__(256, 3) void router_pass1(
    const float* __restrict__ x,        // [T, H] fp32
    const _Float16* __restrict__ whi,   // [E, H] fp16
    const _Float16* __restrict__ wlo,   // [E, H] fp16 (x 2^11)
    const float* __restrict__ bias,
    float* __restrict__ out_w, float* __restrict__ out_i,
    unsigned int* __restrict__ mask, int T, int H) {
  __shared__ char lds[33792];
  // B buf0: hi @0 (8KB), lo @8192; buf1: hi @16384, lo @24576.
  // Epilogue reuse: logits fp32 [64][132] @0 (33792 B).

  const int tid = threadIdx.x;
  const int t0  = blockIdx.x * 64;
  const int l   = tid & 63;
  const int wv  = tid >> 6;
  const int wm  = wv & 1;              // token half (32)
  const int wn  = wv >> 1;             // expert half (64)

  // ---- W DMA: per-lane pre-swizzled global source offsets (k0-invariant) ----
  // Linear LDS offset o -> (row, kb) under the adr() packing (R10-validated).
  int soff0, soff1;
  {
    const int o0   = wv * 1024 + l * 16;
    const int ln0  = o0 >> 7;
    const int un0  = (o0 & 127) ^ ((ln0 & 7) << 4);
    soff0 = (ln0 * 2 + (un0 >> 6)) * (H * 2) + (un0 & 63);
    const int o1   = 4096 + wv * 1024 + l * 16;
    const int ln1  = o1 >> 7;
    const int un1  = (o1 & 127) ^ ((ln1 & 7) << 4);
    soff1 = (ln1 * 2 + (un1 >> 6)) * (H * 2) + (un1 & 63);
  }
  const int dst0 = wv * 1024;          // wave-uniform LDS dest offsets
  const int dst1 = 4096 + wv * 1024;

  // ---- A: per-lane direct global pointers (row = (l&15), k-slice = (l>>4)*8) ----
  const float* a0 = x + (size_t)(t0 + wm * 32 + (l & 15)) * H + (l >> 4) * 8;
  const float* a1 = a0 + (size_t)16 * H;   // mt=1 row

  f4 acc1[2][4], acc2[2][4];
#pragma unroll
  for (int mt = 0; mt < 2; ++mt)
#pragma unroll
    for (int nt = 0; nt < 4; ++nt) { acc1[mt][nt] = (f4)0.0f; acc2[mt][nt] = (f4)0.0f; }

  // ---- prologue: DMA B tile0 -> buf0; load A fragments tile0 ----
  {
    GLOAD_LDS16((const char*)whi + soff0, lds + dst0);
    GLOAD_LDS16((const char*)whi + soff1, lds + dst1);
    GLOAD_LDS16((const char*)wlo + soff0, lds + 8192 + dst0);
    GLOAD_LDS16((const char*)wlo + soff1, lds + 8192 + dst1);
  }
  float4 pA00 = *(const float4*)(a0);
  float4 pA01 = *(const float4*)(a0 + 4);
  float4 pA10 = *(const float4*)(a1);
  float4 pA11 = *(const float4*)(a1 + 4);

  for (int k0 = 0; k0 < H; k0 += 32) {
    const int cur = (k0 >> 5) & 1;
    __syncthreads();   // drains B[cur] DMA (+ pA loads); B[cur^1] free to overwrite

    // ---- issue next tile's B DMA into the other buffer ----
    if (k0 + 32 < H) {
      const char* whb = (const char*)whi + (size_t)(k0 + 32) * 2;
      const char* wlb = (const char*)wlo + (size_t)(k0 + 32) * 2;
      const int nb = (cur ^ 1) * 16384;
      GLOAD_LDS16(whb + soff0, lds + nb + dst0);
      GLOAD_LDS16(whb + soff1, lds + nb + dst1);
      GLOAD_LDS16(wlb + soff0, lds + nb + 8192 + dst0);
      GLOAD_LDS16(wlb + soff1, lds + nb + 8192 + dst1);
    }

    // ---- convert A prefetch regs -> hi/lo fragments (this tile) ----
    h8 Ah[2], Al[2];
#pragma unroll
    for (int q = 0; q < 4; ++q) {
      {
        const float v0 = ((const float*)&pA00)[q];
        const float v1 = ((const float*)&pA01)[q];
        const _Float16 h0 = (_Float16)v0;
        const _Float16 h1 = (_Float16)v1;
        Ah[0][q] = h0; Ah[0][4 + q] = h1;
        Al[0][q]     = (_Float16)((v0 - (float)h0) * 2048.0f);
        Al[0][4 + q] = (_Float16)((v1 - (float)h1) * 2048.0f);
      }
      {
        const float v0 = ((const float*)&pA10)[q];
        const float v1 = ((const float*)&pA11)[q];
        const _Float16 h0 = (_Float16)v0;
        const _Float16 h1 = (_Float16)v1;
        Ah[1][q] = h0; Ah[1][4 + q] = h1;
        Al[1][q]     = (_Float16)((v0 - (float)h0) * 2048.0f);
        Al[1][4 + q] = (_Float16)((v1 - (float)h1) * 2048.0f);
      }
    }

    // ---- issue next tile's A loads (drained at next barrier) ----
    if (k0 + 32 < H) {
      pA00 = *(const float4*)(a0 + k0 + 32);
      pA01 = *(const float4*)(a0 + k0 + 36);
      pA10 = *(const float4*)(a1 + k0 + 32);
      pA11 = *(const float4*)(a1 + k0 + 36);
    }

    // ---- MFMA on B[cur] ----
    const int bb  = cur * 16384;
    const int kbb = (l >> 4) * 16;
#pragma unroll
    for (int nt = 0; nt < 4; ++nt) {
      const int er = wn * 64 + nt * 16 + (l & 15);
      const h8 Bh = *(const h8*)(lds + bb        + adr(er, kbb));
      const h8 Bl = *(const h8*)(lds + bb + 8192 + adr(er, kbb));
#pragma unroll
      for (int mt = 0; mt < 2; ++mt) {
        acc1[mt][nt] = __builtin_amdgcn_mfma_f32_16x16x32_f16(Ah[mt], Bh, acc1[mt][nt], 0, 0, 0);
        acc2[mt][nt] = __builtin_amdgcn_mfma_f32_16x16x32_f16(Ah[mt], Bl, acc2[mt][nt], 0, 0, 0);
        acc2[mt][nt] = __builtin_amdgcn_mfma_f32_16x16x32_f16(Al[mt], Bh, acc2[mt][nt], 0, 0, 0);
      }
    }
  }

  // ---- dump logits to LDS (C/D layout: col=lane&15, row=(lane>>4)*4+r) ----
  __syncthreads();
  float* logits = (float*)lds;
#pragma unroll
  for (int mt = 0; mt < 2; ++mt)
#pragma unroll
    for (int nt = 0; nt < 4; ++nt)
#pragma unroll
      for (int r = 0; r < 4; ++r) {
        const int row = wm * 32 + mt * 16 + (l >> 4) * 4 + r;
        const int col = wn * 64 + nt * 16 + (l & 15);
        logits[row * 132 + col] = acc1[mt][nt][r] + acc2[mt][nt][r] * (1.0f / 2048.0f);
      }
  __syncthreads();

  // ---- epilogue: sigmoid, top-8 across 16-lane groups, flag near-ties ----
  const int tx    = tid & 15;
  const int g     = tid >> 4;          // 16 groups x 4 tokens
  const int lane  = tid & 63;
  const int gbase = lane & 48;

  float biasr[8];
#pragma unroll
  for (int j = 0; j < 4; ++j) {
    biasr[j]     = bias[tx * 4 + j];
    biasr[4 + j] = bias[64 + tx * 4 + j];
  }

#pragma unroll
  for (int it = 0; it < 4; ++it) {
    const int tok = g * 4 + it;
    const float4 lo4 = *(const float4*)(logits + tok * 132 + tx * 4);
    const float4 hi4 = *(const float4*)(logits + tok * 132 + 64 + tx * 4);
    float sc[8], bal[8];
#pragma unroll
    for (int j = 0; j < 4; ++j) {
      sc[j]     = 1.f / (1.f + expf(-((const float*)&lo4)[j]));
      sc[4 + j] = 1.f / (1.f + expf(-((const float*)&hi4)[j]));
    }
#pragma unroll
    for (int j = 0; j < 8; ++j) bal[j] = sc[j] + biasr[j];

    float myw[TOPK];
    int   myid[TOPK];
    float prev = 0.f;
    int   flagged = 0;
#pragma unroll
    for (int r = 0; r < TOPK + 1; ++r) {
      float bv = bal[0];
      int   bi = tx * 4;
#pragma unroll
      for (int j = 1; j < 8; ++j) {
        const int ej = (j < 4) ? (tx * 4 + j) : (64 + tx * 4 + (j - 4));
        if (bal[j] > bv) { bv = bal[j]; bi = ej; }
      }
#pragma unroll
      for (int m = 1; m <= 8; m <<= 1) {
        const float ov = __shfl_xor(bv, m);
        const int   oi = __shfl_xor(bi, m);
        if (ov > bv || (ov == bv && oi < bi)) { bv = ov; bi = oi; }
      }
      if (r > 0 && (prev - bv) < MARGIN) flagged = 1;
      prev = bv;
      if (r < TOPK) {
        const int ls = (bi < 64) ? (bi >> 2) : ((bi - 64) >> 2);
        const int jt = (bi < 64) ? (bi & 3) : (4 + ((bi - 64) & 3));
        const float a0s = (jt & 1) ? sc[1] : sc[0];
        const float a1s = (jt & 1) ? sc[3] : sc[2];
        const float a2s = (jt & 1) ? sc[5] : sc[4];
        const float a3s = (jt & 1) ? sc[7] : sc[6];
        const float b0s = (jt & 2) ? a1s : a0s;
        const float b1s = (jt & 2) ? a3s : a2s;
        const float sv = (jt & 4) ? b1s : b0s;
        const float sw = __shfl(sv, gbase | ls);
        myw[r]  = sw;
        myid[r] = bi;
#pragma unroll
        for (int j = 0; j < 8; ++j)
          if (tx == ls && j == jt) bal[j] = -INFINITY;
      }
    }

    if (tx == 0) {
      float den = 0.f;
#pragma unroll
      for (int r = 0; r < TOPK; ++r) den += fabsf(myw[r]);
      den = fmaxf(den, 1e-12f);
      const int t = t0 + tok;
      float4* wo = (float4*)(out_w + (size_t)t * TOPK);
      float4* io = (float4*)(out_i + (size_t)t * TOPK);
      wo[0] = make_float4(myw[0] / den, myw[1] / den, myw[2] / den, myw[3] / den);
      wo[1] = make_float4(myw[4] / den, myw[5] / den, myw[6] / den, myw[7] / den);
      io[0] = make_float4((float)myid[0], (float)myid[1], (float)myid[2], (float)myid[3]);
      io[1] = make_float4((float)myid[4], (float)myid[5], (float)myid[6], (float)myid[7]);
      if (flagged) atomicOr(&mask[t >> 5], 1u << (t & 31));
    }
  }
}

// ---------------- Compaction: bitmask -> ordered token list (deterministic) ----------------
__global__ __launch_bounds__(1024) void router_compact(
    const unsigned int* __restrict__ mask, int* __restrict__ cnt,
    int* __restrict__ flags, int nwords) {
  __shared__ int wsum[17];
  const int tid = threadIdx.x;
  unsigned int w = (tid < nwords) ? mask[tid] : 0u;
  const int c = __popc(w);
  const int lane = tid & 63;
  const int wv   = tid >> 6;
  int inc = c;
#pragma unroll
  for (int m = 1; m < 64; m <<= 1) {
    const int v = __shfl_up(inc, m);
    if (lane >= m) inc += v;
  }
  if (lane == 63) wsum[wv + 1] = inc;
  __syncthreads();
  if (tid == 0) {
    wsum[0] = 0;
    for (int i = 1; i <= 16; ++i) wsum[i] += wsum[i - 1];
    cnt[0] = wsum[16];
  }
  __syncthreads();
  int off = wsum[wv] + inc - c;
  while (w) {
    const int b = __ffs(w) - 1;
    w &= w - 1u;
    flags[off++] = tid * 32 + b;
  }
}

// ---------------- Pass 2: fp64 recompute, ONE token per block (grid-stride) ----------------
__global__ __launch_bounds__(256) void router_pass2(
    const float* __restrict__ x, const float* __restrict__ W,
    const float* __restrict__ bias,
    float* __restrict__ out_w, float* __restrict__ out_i,
    const int* __restrict__ cnt, const int* __restrict__ flags, int H) {
  __shared__ float  xs[4096];          // 16 KB (H == 4096)
  __shared__ double red[NE];

  const int tid = threadIdx.x;
  const int e   = tid & 127;
  const int h   = tid >> 7;
  const int count = cnt[0];

  for (int i = blockIdx.x; i < count; i += gridDim.x) {
    const int t = flags[i];

    __syncthreads();
    {
      const float* xp = x + (size_t)t * H;
#pragma unroll
      for (int c = 0; c < 4; ++c) {
        const int fi = (c * 256 + tid) * 4;
        *(float4*)(xs + fi) = *(const float4*)(xp + fi);
      }
    }
    __syncthreads();

    double a0 = 0.0, a1 = 0.0, a2 = 0.0, a3 = 0.0;
    {
      const float* wp = W + (size_t)e * H + h * 2048;
      const float* xb = xs + h * 2048;
      for (int kk = 0; kk < 2048; kk += 4) {
        const float4 wv = *(const float4*)(wp + kk);
        const float4 xv = *(const float4*)(xb + kk);
        a0 = fma((double)xv.x, (double)wv.x, a0);
        a1 = fma((double)xv.y, (double)wv.y, a1);
        a2 = fma((double)xv.z, (double)wv.z, a2);
        a3 = fma((double)xv.w, (double)wv.w, a3);
      }
    }
    const double a = (a0 + a1) + (a2 + a3);

    if (h == 1) red[e] = a;
    __syncthreads();
    if (h == 0) red[e] = 1.0 / (1.0 + exp(-(a + red[e])));
    __syncthreads();

    if (tid < 64) {
      const int l = tid;
      const double s0 = red[l];
      const double s1 = red[64 + l];
      double g0 = s0 + (double)bias[l];
      double g1 = s1 + (double)bias[64 + l];
      double myw[TOPK]; int myid[TOPK];
#pragma unroll
      for (int r = 0; r < TOPK; ++r) {
        double bv; int bi;
        if (g1 > g0) { bv = g1; bi = 64 + l; } else { bv = g0; bi = l; }
#pragma unroll
        for (int m = 1; m <= 32; m <<= 1) {
          const double ov = __shfl_xor(bv, m);
          const int    oi = __shfl_xor(bi, m);
          if (ov > bv || (ov == bv && oi < bi)) { bv = ov; bi = oi; }
        }
        const int ls   = bi & 63;
        const int slot = bi >> 6;
        const double sv = slot ? s1 : s0;
        const double sw = __shfl(sv, ls);
        myw[r]  = sw;
        myid[r] = bi;
        if (l == ls) { if (slot) g1 = -INFINITY; else g0 = -INFINITY; }
      }
      if (l == 0) {
        double den = 0.0;
#pragma unroll
        for (int r = 0; r < TOPK; ++r) den += fabs(myw[r]);
        den = fmax(den, 1e-12);
#pragma unroll
        for (int r = 0; r < TOPK; ++r) {
          out_w[(size_t)t * TOPK + r] = (float)(myw[r] / den);
          out_i[(size_t)t * TOPK + r] = (float)myid[r];
        }
      }
    }
  }
}

extern "C" void kernel_launch(void* const* d_in, const int* in_sizes, int n_in,
                              void* d_out, int out_size, void* d_ws, size_t ws_size,
                              hipStream_t stream) {
  const float* x    = (const float*)d_in[0];
  const float* W    = (const float*)d_in[1];
  const float* bias = (const float*)d_in[2];
  const int E = in_sizes[2];            // 128
  const int H = in_sizes[1] / E;        // 4096
  const int T = in_sizes[0] / H;        // 32768
  (void)E; (void)n_in; (void)ws_size; (void)out_size;

  float* out_w = (float*)d_out;
  float* out_i = out_w + (size_t)T * TOPK;

  // workspace layout (bytes): whi [1MB] | wlo [1MB] | mask [4KB] | cnt [16B] | flags
  char* ws = (char*)d_ws;
  _Float16* whi = (_Float16*)ws;
  _Float16* wlo = (_Float16*)(ws + (1 << 20));
  unsigned int* mask = (unsigned int*)(ws + (2 << 20));
  const int nwords = (T + 31) / 32;     // 1024
  int* cnt   = (int*)(ws + (2 << 20) + nwords * 4);
  int* flags = (int*)(ws + (2 << 20) + nwords * 4 + 16);

  hipMemsetAsync(mask, 0, (size_t)nwords * 4 + 16, stream);

  const int n4 = (E * H) / 4;           // 131072 float4s
  router_wsplit<<<dim3((n4 + 255) / 256), dim3(256), 0, stream>>>(W, whi, wlo, n4);
  router_pass1<<<dim3(T / 64), dim3(256), 0, stream>>>(x, whi, wlo, bias, out_w, out_i, mask, T, H);
  router_compact<<<dim3(1), dim3(1024), 0, stream>>>(mask, cnt, flags, nwords);
  router_pass2<<<dim3(2048), dim3(256), 0, stream>>>(x, W, bias, out_w, out_i, cnt, flags, H);
}

// Round 12
// 309.279 us; speedup vs baseline: 1.3110x; 1.3110x over previous
//
#include <hip/hip_runtime.h>
#include <math.h>

#define TOPK 8
#define NE   128
#define MARGIN 1.5e-5f

typedef _Float16 h8 __attribute__((ext_vector_type(8)));
typedef _Float16 h4 __attribute__((ext_vector_type(4)));
typedef float    f4 __attribute__((ext_vector_type(4)));

// byte address within a [row][64 halfs] LDS tile (128 B row stride),
// XOR-swizzled so 16-lane column reads spread across banks. (R8-validated)
__device__ __forceinline__ int swz(int row, int kb) {
  return row * 128 + (kb ^ ((row & 7) << 4));
}

#define GLOAD_LDS16(g, l)                                              \
  __builtin_amdgcn_global_load_lds(                                    \
      (const __attribute__((address_space(1))) void*)(g),              \
      (__attribute__((address_space(3))) void*)(l), 16, 0, 0)

// ---------------- Kernel 0: split W into fp16 hi + scaled lo ----------------
__global__ __launch_bounds__(256) void router_wsplit(
    const float* __restrict__ W, _Float16* __restrict__ whi,
    _Float16* __restrict__ wlo, int n4) {
  const int i = blockIdx.x * 256 + threadIdx.x;
  if (i < n4) {
    const float4 v = ((const float4*)W)[i];
    h4 hi, lo;
#pragma unroll
    for (int q = 0; q < 4; ++q) {
      const float vq = ((const float*)&v)[q];
      const _Float16 h = (_Float16)vq;
      hi[q] = h;
      lo[q] = (_Float16)((vq - (float)h) * 2048.0f);  // lo' = lo * 2^11
    }
    ((h4*)whi)[i] = hi;
    ((h4*)wlo)[i] = lo;
  }
}

// ---------------- Pass 1: split-fp16 MFMA GEMM + sigmoid + top-8 + flag ----------------
// 512 threads = 8 waves; tile 64 tok x 128 exp; BK=64; 48KB LDS -> 2 blocks/CU
// (16 waves/CU, 4/SIMD). Wave tile 32 tok x 32 exp (mt=2, nt=2).
// W via global_load_lds (pre-swizzled source); x via reg-prefetch issued after
// barrier2 (hides under MFMA, drained at next barrier1). R8 structure, 2x waves.
__global__ __launch_bounds__(512, 2) void router_pass1(
    const float* __restrict__ x,        // [T, H] fp32
    const _Float16* __restrict__ whi,   // [E, H] fp16
    const _Float16* __restrict__ wlo,   // [E, H] fp16 (x 2^11)
    const float* __restrict__ bias,
    float* __restrict__ out_w, float* __restrict__ out_i,
    unsigned int* __restrict__ mask, int T, int H) {
  __shared__ char lds[49152];
  // A_hi @0 (8KB: 64 rows x 128B), A_lo @8192, B_hi @16384 (16KB: 128 rows),
  // B_lo @32768. Epilogue reuse: logits fp32 [64][132] @0 (33.8 KB).

  const int tid = threadIdx.x;
  const int t0  = blockIdx.x * 64;
  const int l   = tid & 63;
  const int wv  = tid >> 6;            // 0..7
  const int wm  = wv & 1;              // token half (32)
  const int wn  = wv >> 1;             // expert quarter (32)

  // x staging: thread -> row tid>>3 (0..63), k-octet (tid&7)*8
  const int xrow = tid >> 3;
  const int xk   = (tid & 7) * 8;
  const float* xptr = x + (size_t)(t0 + xrow) * H + xk;
  const int aw = swz(xrow, (tid & 7) * 16);   // A write byte-addr (hi; lo at +8192)

  // W DMA: 2 chunks/thread per 16KB half (16 chunks, 8 waves x 2).
  // Linear LDS offset o -> (row, kb) inverse of swz (R8-validated).
  int soff0, soff1;
  {
    const int o0  = (wv * 2) * 1024 + l * 16;
    const int r0  = o0 >> 7;
    soff0 = r0 * (H * 2) + ((o0 & 127) ^ ((r0 & 7) << 4));
    const int o1  = (wv * 2 + 1) * 1024 + l * 16;
    const int r1  = o1 >> 7;
    soff1 = r1 * (H * 2) + ((o1 & 127) ^ ((r1 & 7) << 4));
  }
  const int dst0 = (wv * 2) * 1024;
  const int dst1 = (wv * 2 + 1) * 1024;

  f4 acc1[2][2], acc2[2][2];
#pragma unroll
  for (int mt = 0; mt < 2; ++mt)
#pragma unroll
    for (int nt = 0; nt < 2; ++nt) { acc1[mt][nt] = (f4)0.0f; acc2[mt][nt] = (f4)0.0f; }

  float4 px0 = *(const float4*)(xptr);
  float4 px1 = *(const float4*)(xptr + 4);

  for (int k0 = 0; k0 < H; k0 += 64) {
    __syncthreads();                   // barrier1: prev LDS reads done; drains px
    // ---- issue W DMA for THIS tile (hi -> 16384+, lo -> 32768+) ----
    {
      const char* whb = (const char*)whi + (size_t)k0 * 2;
      const char* wlb = (const char*)wlo + (size_t)k0 * 2;
      GLOAD_LDS16(whb + soff0, lds + 16384 + dst0);
      GLOAD_LDS16(whb + soff1, lds + 16384 + dst1);
      GLOAD_LDS16(wlb + soff0, lds + 32768 + dst0);
      GLOAD_LDS16(wlb + soff1, lds + 32768 + dst1);
    }
    // ---- x: convert staged regs to hi/lo fp16, write swizzled ----
    {
      h8 hi, lo;
      const float* pv0 = (const float*)&px0;
      const float* pv1 = (const float*)&px1;
#pragma unroll
      for (int q = 0; q < 4; ++q) {
        const _Float16 h0 = (_Float16)pv0[q];
        const _Float16 h1 = (_Float16)pv1[q];
        hi[q] = h0; hi[4 + q] = h1;
        lo[q]     = (_Float16)((pv0[q] - (float)h0) * 2048.0f);
        lo[4 + q] = (_Float16)((pv1[q] - (float)h1) * 2048.0f);
      }
      *(h8*)(lds + aw)        = hi;
      *(h8*)(lds + 8192 + aw) = lo;
    }
    __syncthreads();                   // barrier2: drains W DMA; tile ready

    // ---- issue next x tile NOW (drained at next barrier1, full MFMA cover) ----
    if (k0 + 64 < H) {
      px0 = *(const float4*)(xptr + k0 + 64);
      px1 = *(const float4*)(xptr + k0 + 68);
    }

    // ---- MFMA over two K=32 steps ----
#pragma unroll
    for (int ks = 0; ks < 2; ++ks) {
      const int kb = ks * 64 + ((l >> 4) * 16);
      h8 Ah[2], Al[2];
#pragma unroll
      for (int mt = 0; mt < 2; ++mt) {
        const int row = wm * 32 + mt * 16 + (l & 15);
        Ah[mt] = *(const h8*)(lds +        swz(row, kb));
        Al[mt] = *(const h8*)(lds + 8192 + swz(row, kb));
      }
#pragma unroll
      for (int nt = 0; nt < 2; ++nt) {
        const int er = wn * 32 + nt * 16 + (l & 15);
        const h8 Bh = *(const h8*)(lds + 16384 + swz(er, kb));
        const h8 Bl = *(const h8*)(lds + 32768 + swz(er, kb));
#pragma unroll
        for (int mt = 0; mt < 2; ++mt) {
          acc1[mt][nt] = __builtin_amdgcn_mfma_f32_16x16x32_f16(Ah[mt], Bh, acc1[mt][nt], 0, 0, 0);
          acc2[mt][nt] = __builtin_amdgcn_mfma_f32_16x16x32_f16(Ah[mt], Bl, acc2[mt][nt], 0, 0, 0);
          acc2[mt][nt] = __builtin_amdgcn_mfma_f32_16x16x32_f16(Al[mt], Bh, acc2[mt][nt], 0, 0, 0);
        }
      }
    }
  }

  // ---- dump logits to LDS (C/D layout: col=lane&15, row=(lane>>4)*4+r) ----
  __syncthreads();
  float* logits = (float*)lds;
#pragma unroll
  for (int mt = 0; mt < 2; ++mt)
#pragma unroll
    for (int nt = 0; nt < 2; ++nt)
#pragma unroll
      for (int r = 0; r < 4; ++r) {
        const int row = wm * 32 + mt * 16 + (l >> 4) * 4 + r;
        const int col = wn * 32 + nt * 16 + (l & 15);
        logits[row * 132 + col] = acc1[mt][nt][r] + acc2[mt][nt][r] * (1.0f / 2048.0f);
      }
  __syncthreads();

  // ---- epilogue: sigmoid, top-8 across 16-lane groups, flag near-ties ----
  const int tx    = tid & 15;
  const int g     = tid >> 4;          // 32 groups x 2 tokens
  const int lane  = tid & 63;
  const int gbase = lane & 48;

  float biasr[8];
#pragma unroll
  for (int j = 0; j < 4; ++j) {
    biasr[j]     = bias[tx * 4 + j];
    biasr[4 + j] = bias[64 + tx * 4 + j];
  }

#pragma unroll
  for (int it = 0; it < 2; ++it) {
    const int tok = g * 2 + it;
    const float4 lo4 = *(const float4*)(logits + tok * 132 + tx * 4);
    const float4 hi4 = *(const float4*)(logits + tok * 132 + 64 + tx * 4);
    float sc[8], bal[8];
#pragma unroll
    for (int j = 0; j < 4; ++j) {
      sc[j]     = 1.f / (1.f + expf(-((const float*)&lo4)[j]));
      sc[4 + j] = 1.f / (1.f + expf(-((const float*)&hi4)[j]));
    }
#pragma unroll
    for (int j = 0; j < 8; ++j) bal[j] = sc[j] + biasr[j];

    float myw[TOPK];
    int   myid[TOPK];
    float prev = 0.f;
    int   flagged = 0;
#pragma unroll
    for (int r = 0; r < TOPK + 1; ++r) {
      float bv = bal[0];
      int   bi = tx * 4;
#pragma unroll
      for (int j = 1; j < 8; ++j) {
        const int ej = (j < 4) ? (tx * 4 + j) : (64 + tx * 4 + (j - 4));
        if (bal[j] > bv) { bv = bal[j]; bi = ej; }
      }
#pragma unroll
      for (int m = 1; m <= 8; m <<= 1) {
        const float ov = __shfl_xor(bv, m);
        const int   oi = __shfl_xor(bi, m);
        if (ov > bv || (ov == bv && oi < bi)) { bv = ov; bi = oi; }
      }
      if (r > 0 && (prev - bv) < MARGIN) flagged = 1;
      prev = bv;
      if (r < TOPK) {
        const int ls = (bi < 64) ? (bi >> 2) : ((bi - 64) >> 2);
        const int jt = (bi < 64) ? (bi & 3) : (4 + ((bi - 64) & 3));
        const float a0s = (jt & 1) ? sc[1] : sc[0];
        const float a1s = (jt & 1) ? sc[3] : sc[2];
        const float a2s = (jt & 1) ? sc[5] : sc[4];
        const float a3s = (jt & 1) ? sc[7] : sc[6];
        const float b0s = (jt & 2) ? a1s : a0s;
        const float b1s = (jt & 2) ? a3s : a2s;
        const float sv = (jt & 4) ? b1s : b0s;
        const float sw = __shfl(sv, gbase | ls);
        myw[r]  = sw;
        myid[r] = bi;
#pragma unroll
        for (int j = 0; j < 8; ++j)
          if (tx == ls && j == jt) bal[j] = -INFINITY;
      }
    }

    if (tx == 0) {
      float den = 0.f;
#pragma unroll
      for (int r = 0; r < TOPK; ++r) den += fabsf(myw[r]);
      den = fmaxf(den, 1e-12f);
      const int t = t0 + tok;
      float4* wo = (float4*)(out_w + (size_t)t * TOPK);
      float4* io = (float4*)(out_i + (size_t)t * TOPK);
      wo[0] = make_float4(myw[0] / den, myw[1] / den, myw[2] / den, myw[3] / den);
      wo[1] = make_float4(myw[4] / den, myw[5] / den, myw[6] / den, myw[7] / den);
      io[0] = make_float4((float)myid[0], (float)myid[1], (float)myid[2], (float)myid[3]);
      io[1] = make_float4((float)myid[4], (float)myid[5], (float)myid[6], (float)myid[7]);
      if (flagged) atomicOr(&mask[t >> 5], 1u << (t & 31));
    }
  }
}

// ---------------- Compaction: bitmask -> ordered token list (deterministic) ----------------
__global__ __launch_bounds__(1024) void router_compact(
    const unsigned int* __restrict__ mask, int* __restrict__ cnt,
    int* __restrict__ flags, int nwords) {
  __shared__ int wsum[17];
  const int tid = threadIdx.x;
  unsigned int w = (tid < nwords) ? mask[tid] : 0u;
  const int c = __popc(w);
  const int lane = tid & 63;
  const int wv   = tid >> 6;
  int inc = c;
#pragma unroll
  for (int m = 1; m < 64; m <<= 1) {
    const int v = __shfl_up(inc, m);
    if (lane >= m) inc += v;
  }
  if (lane == 63) wsum[wv + 1] = inc;
  __syncthreads();
  if (tid == 0) {
    wsum[0] = 0;
    for (int i = 1; i <= 16; ++i) wsum[i] += wsum[i - 1];
    cnt[0] = wsum[16];
  }
  __syncthreads();
  int off = wsum[wv] + inc - c;
  while (w) {
    const int b = __ffs(w) - 1;
    w &= w - 1u;
    flags[off++] = tid * 32 + b;
  }
}

// ---------------- Pass 2: fp64 recompute, ONE token per block (grid-stride) ----------------
__global__ __launch_bounds__(256) void router_pass2(
    const float* __restrict__ x, const float* __restrict__ W,
    const float* __restrict__ bias,
    float* __restrict__ out_w, float* __restrict__ out_i,
    const int* __restrict__ cnt, const int* __restrict__ flags, int H) {
  __shared__ float  xs[4096];          // 16 KB (H == 4096)
  __shared__ double red[NE];

  const int tid = threadIdx.x;
  const int e   = tid & 127;
  const int h   = tid >> 7;
  const int count = cnt[0];

  for (int i = blockIdx.x; i < count; i += gridDim.x) {
    const int t = flags[i];

    __syncthreads();
    {
      const float* xp = x + (size_t)t * H;
#pragma unroll
      for (int c = 0; c < 4; ++c) {
        const int fi = (c * 256 + tid) * 4;
        *(float4*)(xs + fi) = *(const float4*)(xp + fi);
      }
    }
    __syncthreads();

    double a0 = 0.0, a1 = 0.0, a2 = 0.0, a3 = 0.0;
    {
      const float* wp = W + (size_t)e * H + h * 2048;
      const float* xb = xs + h * 2048;
      for (int kk = 0; kk < 2048; kk += 4) {
        const float4 wv = *(const float4*)(wp + kk);
        const float4 xv = *(const float4*)(xb + kk);
        a0 = fma((double)xv.x, (double)wv.x, a0);
        a1 = fma((double)xv.y, (double)wv.y, a1);
        a2 = fma((double)xv.z, (double)wv.z, a2);
        a3 = fma((double)xv.w, (double)wv.w, a3);
      }
    }
    const double a = (a0 + a1) + (a2 + a3);

    if (h == 1) red[e] = a;
    __syncthreads();
    if (h == 0) red[e] = 1.0 / (1.0 + exp(-(a + red[e])));
    __syncthreads();

    if (tid < 64) {
      const int l = tid;
      const double s0 = red[l];
      const double s1 = red[64 + l];
      double g0 = s0 + (double)bias[l];
      double g1 = s1 + (double)bias[64 + l];
      double myw[TOPK]; int myid[TOPK];
#pragma unroll
      for (int r = 0; r < TOPK; ++r) {
        double bv; int bi;
        if (g1 > g0) { bv = g1; bi = 64 + l; } else { bv = g0; bi = l; }
#pragma unroll
        for (int m = 1; m <= 32; m <<= 1) {
          const double ov = __shfl_xor(bv, m);
          const int    oi = __shfl_xor(bi, m);
          if (ov > bv || (ov == bv && oi < bi)) { bv = ov; bi = oi; }
        }
        const int ls   = bi & 63;
        const int slot = bi >> 6;
        const double sv = slot ? s1 : s0;
        const double sw = __shfl(sv, ls);
        myw[r]  = sw;
        myid[r] = bi;
        if (l == ls) { if (slot) g1 = -INFINITY; else g0 = -INFINITY; }
      }
      if (l == 0) {
        double den = 0.0;
#pragma unroll
        for (int r = 0; r < TOPK; ++r) den += fabs(myw[r]);
        den = fmax(den, 1e-12);
#pragma unroll
        for (int r = 0; r < TOPK; ++r) {
          out_w[(size_t)t * TOPK + r] = (float)(myw[r] / den);
          out_i[(size_t)t * TOPK + r] = (float)myid[r];
        }
      }
    }
  }
}

extern "C" void kernel_launch(void* const* d_in, const int* in_sizes, int n_in,
                              void* d_out, int out_size, void* d_ws, size_t ws_size,
                              hipStream_t stream) {
  const float* x    = (const float*)d_in[0];
  const float* W    = (const float*)d_in[1];
  const float* bias = (const float*)d_in[2];
  const int E = in_sizes[2];            // 128
  const int H = in_sizes[1] / E;        // 4096
  const int T = in_sizes[0] / H;        // 32768
  (void)E; (void)n_in; (void)ws_size; (void)out_size;

  float* out_w = (float*)d_out;
  float* out_i = out_w + (size_t)T * TOPK;

  // workspace layout (bytes): whi [1MB] | wlo [1MB] | mask [4KB] | cnt [16B] | flags
  char* ws = (char*)d_ws;
  _Float16* whi = (_Float16*)ws;
  _Float16* wlo = (_Float16*)(ws + (1 << 20));
  unsigned int* mask = (unsigned int*)(ws + (2 << 20));
  const int nwords = (T + 31) / 32;     // 1024
  int* cnt   = (int*)(ws + (2 << 20) + nwords * 4);
  int* flags = (int*)(ws + (2 << 20) + nwords * 4 + 16);

  hipMemsetAsync(mask, 0, (size_t)nwords * 4 + 16, stream);

  const int n4 = (E * H) / 4;           // 131072 float4s
  router_wsplit<<<dim3((n4 + 255) / 256), dim3(256), 0, stream>>>(W, whi, wlo, n4);
  router_pass1<<<dim3(T / 64), dim3(512), 0, stream>>>(x, whi, wlo, bias, out_w, out_i, mask, T, H);
  router_compact<<<dim3(1), dim3(1024), 0, stream>>>(mask, cnt, flags, nwords);
  router_pass2<<<dim3(2048), dim3(256), 0, stream>>>(x, W, bias, out_w, out_i, cnt, flags, H);
}